// Round 9
// baseline (197.277 us; speedup 1.0000x reference)
//
#include <hip/hip_runtime.h>
#include <hip/hip_bf16.h>

typedef __bf16 bf16;
typedef bf16 bf16x8 __attribute__((ext_vector_type(8)));
typedef bf16 bf16x4 __attribute__((ext_vector_type(4)));
typedef float f32x4 __attribute__((ext_vector_type(4)));

#define Bn 8
#define Cdim 256
#define Nn 2304
#define NH 4
#define DH 32
#define HID 128
#define QSCALE (0.17677669529663687f * 1.4426950408889634f)
#define SMAX 14.0f
#define QSZ ((size_t)32 * Nn * DH)
#define WQ_ELEMS (3 * HID * Cdim)
#define WO_ELEMS (Cdim * HID)

// ---------------- Kernel 0: weight cvt + FRAG-MAJOR repack (gather) ----------
__global__ __launch_bounds__(256) void cvt_kernel(const float* __restrict__ wq,
                                                  const float* __restrict__ wo,
                                                  bf16* __restrict__ dst) {
    int d = blockIdx.x * 256 + threadIdx.x;
    {   // wq: 24 o-tiles, 8 kc
        int j = d & 7, lane = (d >> 3) & 63, kc = (d >> 9) & 7, ot = d >> 12;
        int o = ot * 16 + (lane & 15), c = kc * 32 + (lane >> 4) * 8 + j;
        dst[d] = (bf16)wq[o * Cdim + c];
    }
    if (d < WO_ELEMS) {   // wo: 16 o-tiles, 4 kc
        int j = d & 7, lane = (d >> 3) & 63, kc = (d >> 9) & 3, ot = d >> 11;
        int o = ot * 16 + (lane & 15), c = kc * 32 + (lane >> 4) * 8 + j;
        dst[WQ_ELEMS + d] = (bf16)wo[o * HID + c];
    }
}

// ---------------- Kernel 1: QKV projection (direct global gather, no LDS) ----
// Grid (144, 8): 16-px tile per WG; wave w owns o-tiles [w*6, w*6+6).
// Q stored [bh][n][32]; K FRAG-MAJOR; V TRANSPOSED [bh][32][n].
__global__ __launch_bounds__(256) void qkv_kernel(const float* __restrict__ x,
                                                  const bf16* __restrict__ w,
                                                  bf16* __restrict__ ws) {
    const int p0  = blockIdx.x * 16;
    const int b   = blockIdx.y;
    const int tid = threadIdx.x;
    const int lane = tid & 63, w4 = tid >> 6, l16 = lane & 15, quad = lane >> 4;
    const float* xb = x + (size_t)b * Cdim * Nn + p0 + l16;

    // B-frags straight from global: bx[kc][jj] = x[c=kc*32+quad*8+jj][p0+l16]
    bf16x8 bx[8];
    #pragma unroll
    for (int kc = 0; kc < 8; ++kc)
        #pragma unroll
        for (int jj = 0; jj < 8; ++jj)
            bx[kc][jj] = (bf16)xb[(size_t)(kc * 32 + quad * 8 + jj) * Nn];

    const int p = p0 + l16;
    #pragma unroll 1
    for (int oi = 0; oi < 6; ++oi) {
        const int ot = w4 * 6 + oi;
        f32x4 acc0 = {0.f, 0.f, 0.f, 0.f};
        f32x4 acc1 = {0.f, 0.f, 0.f, 0.f};
        #pragma unroll
        for (int kc = 0; kc < 4; ++kc) {
            bf16x8 aw0 = *(const bf16x8*)&w[(((size_t)ot * 8 + kc) * 64 + lane) * 8];
            bf16x8 aw1 = *(const bf16x8*)&w[(((size_t)ot * 8 + kc + 4) * 64 + lane) * 8];
            acc0 = __builtin_amdgcn_mfma_f32_16x16x32_bf16(aw0, bx[kc],     acc0, 0, 0, 0);
            acc1 = __builtin_amdgcn_mfma_f32_16x16x32_bf16(aw1, bx[kc + 4], acc1, 0, 0, 0);
        }
        const int obase = ot * 16 + quad * 4;
        const int t     = obase >> 7;
        const int rem   = obase & 127;
        const int h     = rem >> 5;
        const int dbase = rem & 31;
        if (t == 2) {
            bf16* vt = ws + 2 * QSZ + (size_t)(b * NH + h) * DH * Nn;
            #pragma unroll
            for (int r = 0; r < 4; ++r)
                vt[(size_t)(dbase + r) * Nn + p] = (bf16)(acc0[r] + acc1[r]);
        } else if (t == 1) {
            bf16x4 v4;
            #pragma unroll
            for (int r = 0; r < 4; ++r) v4[r] = (bf16)(acc0[r] + acc1[r]);
            bf16* kf = ws + QSZ + (size_t)(b * NH + h) * Nn * DH;
            const int addr = ((p >> 4) * 64 + (dbase >> 3) * 16 + (p & 15)) * 8 + (dbase & 7);
            *(bf16x4*)&kf[addr] = v4;
        } else {
            bf16x4 v4;
            #pragma unroll
            for (int r = 0; r < 4; ++r) v4[r] = (bf16)((acc0[r] + acc1[r]) * QSCALE);
            size_t addr = ((size_t)(b * NH + h) * Nn + p) * DH + dbase;
            *(bf16x4*)&ws[addr] = v4;
        }
    }
}

// ---------------- Kernel 2: flash attention (64 i-rows/wave: 4x less L2) -----
// Grid 1152, XCD-pinned. WG = 64 Q-rows; wave w owns j-quarter [w*576,+576),
// processes ALL 64 rows (aq[4], o[4][2]): K/V bytes amortize over 4x the MFMA.
// l via VALU adds; split-K combine across the 4 waves in LDS at the end.
__global__ __launch_bounds__(256, 4) void attn_kernel(bf16* __restrict__ ws) {
    __shared__ alignas(16) char smem[34816];   // P: 4x8KB | combine: ob+lb
    const int g   = blockIdx.x;
    const int grp = g >> 3;
    const int bh  = (g & 7) * 4 + grp / 36;
    const int i0  = (grp % 36) * 64;
    const int tid = threadIdx.x;
    const int lane = tid & 63, w4 = tid >> 6, l16 = lane & 15, quad = lane >> 4;
    const int jbase = w4 * 576;

    const bf16* Qb = ws + (size_t)bh * Nn * DH;
    const bf16* Kf = ws + QSZ + (size_t)bh * Nn * DH;       // frag-major
    const bf16* Vt = ws + 2 * QSZ + (size_t)bh * DH * Nn;   // [d][n]

    bf16x8 aq[4];
    #pragma unroll
    for (int it = 0; it < 4; ++it)
        aq[it] = *(const bf16x8*)&Qb[(size_t)(i0 + it * 16 + l16) * DH + quad * 8];

    f32x4 o[4][2];
    #pragma unroll
    for (int it = 0; it < 4; ++it) {
        o[it][0] = {0.f, 0.f, 0.f, 0.f};
        o[it][1] = {0.f, 0.f, 0.f, 0.f};
    }
    float lp[4] = {0.f, 0.f, 0.f, 0.f};
    const f32x4 negM = {-SMAX, -SMAX, -SMAX, -SMAX};

    const int swz = (l16 & 7) << 1;
    int wa[4];
    #pragma unroll
    for (int jt = 0; jt < 4; ++jt)
        wa[jt] = l16 * 64 + (((jt * 4) | quad) ^ swz) * 4;
    const int ra0 = l16 * 64 + ((quad * 2) ^ swz) * 4;
    const int ra1 = l16 * 64 + ((8 | (quad * 2)) ^ swz) * 4;
    bf16* pbuf = (bf16*)smem + w4 * 4096;

    bf16x8 kf[4];
    {   const bf16* kp = &Kf[(size_t)(jbase >> 4) * 512 + lane * 8];
        #pragma unroll
        for (int jt = 0; jt < 4; ++jt) kf[jt] = *(const bf16x8*)&kp[jt * 512];
    }

    #pragma unroll 1
    for (int cc = 0; cc < 9; ++cc) {
        const int j0 = jbase + cc * 64;
        const bf16* vp = &Vt[j0];
        bf16x8 bv0 = *(const bf16x8*)&vp[(size_t)l16 * Nn + quad * 8];
        bf16x8 bv1 = *(const bf16x8*)&vp[(size_t)l16 * Nn + 32 + quad * 8];
        bf16x8 bv2 = *(const bf16x8*)&vp[(size_t)(l16 + 16) * Nn + quad * 8];
        bf16x8 bv3 = *(const bf16x8*)&vp[(size_t)(l16 + 16) * Nn + 32 + quad * 8];

        #pragma unroll
        for (int it = 0; it < 4; ++it)
            #pragma unroll
            for (int jt = 0; jt < 4; ++jt) {
                f32x4 st = __builtin_amdgcn_mfma_f32_16x16x32_bf16(kf[jt], aq[it], negM, 0, 0, 0);
                float e0 = __builtin_amdgcn_exp2f(st[0]);
                float e1 = __builtin_amdgcn_exp2f(st[1]);
                float e2 = __builtin_amdgcn_exp2f(st[2]);
                float e3 = __builtin_amdgcn_exp2f(st[3]);
                lp[it] += (e0 + e1) + (e2 + e3);
                bf16x4 pv4 = {(bf16)e0, (bf16)e1, (bf16)e2, (bf16)e3};
                *(bf16x4*)&pbuf[it * 1024 + wa[jt]] = pv4;
            }
        if (cc != 8) {   // prefetch next K (after all QK reads of kf)
            const bf16* kp = &Kf[(size_t)((j0 + 64) >> 4) * 512 + lane * 8];
            #pragma unroll
            for (int jt = 0; jt < 4; ++jt) kf[jt] = *(const bf16x8*)&kp[jt * 512];
        }
        #pragma unroll
        for (int it = 0; it < 4; ++it) {
            const bf16x8 ap0 = *(const bf16x8*)&pbuf[it * 1024 + ra0];
            const bf16x8 ap1 = *(const bf16x8*)&pbuf[it * 1024 + ra1];
            o[it][0] = __builtin_amdgcn_mfma_f32_16x16x32_bf16(ap0, bv0, o[it][0], 0, 0, 0);
            o[it][0] = __builtin_amdgcn_mfma_f32_16x16x32_bf16(ap1, bv1, o[it][0], 0, 0, 0);
            o[it][1] = __builtin_amdgcn_mfma_f32_16x16x32_bf16(ap0, bv2, o[it][1], 0, 0, 0);
            o[it][1] = __builtin_amdgcn_mfma_f32_16x16x32_bf16(ap1, bv3, o[it][1], 0, 0, 0);
        }
    }

    // l: finish sum over quads (j-rows within the wave)
    float lt[4];
    #pragma unroll
    for (int it = 0; it < 4; ++it) {
        float v = lp[it];
        v += __shfl_xor(v, 16);
        v += __shfl_xor(v, 32);
        lt[it] = v;
    }

    // ---- split-K combine across the 4 waves (LDS reused) ----
    __syncthreads();
    float* ob = (float*)smem;            // [w][64 rows][33]
    float* lb = ob + 4 * 64 * 33;        // [w][64]
    #pragma unroll
    for (int it = 0; it < 4; ++it) {
        #pragma unroll
        for (int r = 0; r < 4; ++r) {
            ob[(w4 * 64 + it * 16 + quad * 4 + r) * 33 + l16]      = o[it][0][r];
            ob[(w4 * 64 + it * 16 + quad * 4 + r) * 33 + 16 + l16] = o[it][1][r];
        }
        if (quad == 0) lb[w4 * 64 + it * 16 + l16] = lt[it];
    }
    __syncthreads();

    bf16* Ab = ws + 3 * QSZ + (size_t)bh * Nn * DH;
    #pragma unroll
    for (int k = 0; k < 8; ++k) {
        const int idx = k * 256 + tid;
        const int row = idx >> 5, dd = idx & 31;
        float os = ob[row * 33 + dd] + ob[(64 + row) * 33 + dd]
                 + ob[(128 + row) * 33 + dd] + ob[(192 + row) * 33 + dd];
        float lsum = lb[row] + lb[64 + row] + lb[128 + row] + lb[192 + row];
        Ab[(size_t)(i0 + row) * DH + dd] = (bf16)(os / lsum);
    }
}

// ---------------- Kernel 3: output projection (z-split x4) -------------------
__global__ __launch_bounds__(256) void out_kernel(const bf16* __restrict__ wout,
                                                  const float* __restrict__ bout,
                                                  const bf16* __restrict__ Abuf,
                                                  float* __restrict__ out) {
    const int p0  = blockIdx.x * 64;
    const int b   = blockIdx.y;
    const int otb = blockIdx.z * 4;
    const int tid = threadIdx.x;
    const int lane = tid & 63, w4 = tid >> 6, l16 = lane & 15, quad = lane >> 4;
    const int p = p0 + w4 * 16 + l16;

    bf16x8 bfrag[4];
    #pragma unroll
    for (int h = 0; h < NH; ++h)
        bfrag[h] = *(const bf16x8*)&Abuf[((size_t)(b * NH + h) * Nn + p) * DH + quad * 8];

    #pragma unroll 1
    for (int oi = 0; oi < 4; ++oi) {
        const int ot = otb + oi;
        const int o0 = ot * 16;
        float4 b4 = *(const float4*)&bout[o0 + quad * 4];
        f32x4 acc0 = {b4.x, b4.y, b4.z, b4.w};
        f32x4 acc1 = {0.f, 0.f, 0.f, 0.f};
        #pragma unroll
        for (int kc = 0; kc < 2; ++kc) {
            bf16x8 aw0 = *(const bf16x8*)&wout[(((size_t)ot * 4 + kc) * 64 + lane) * 8];
            bf16x8 aw1 = *(const bf16x8*)&wout[(((size_t)ot * 4 + kc + 2) * 64 + lane) * 8];
            acc0 = __builtin_amdgcn_mfma_f32_16x16x32_bf16(aw0, bfrag[kc],     acc0, 0, 0, 0);
            acc1 = __builtin_amdgcn_mfma_f32_16x16x32_bf16(aw1, bfrag[kc + 2], acc1, 0, 0, 0);
        }
        #pragma unroll
        for (int r = 0; r < 4; ++r) {
            const int o = o0 + quad * 4 + r;
            out[((size_t)(b * Cdim + o)) * Nn + p] = acc0[r] + acc1[r];
        }
    }
}

extern "C" void kernel_launch(void* const* d_in, const int* in_sizes, int n_in,
                              void* d_out, int out_size, void* d_ws, size_t ws_size,
                              hipStream_t stream) {
    const float* x     = (const float*)d_in[0];
    const float* w_qkv = (const float*)d_in[1];
    const float* w_out = (const float*)d_in[2];
    const float* b_out = (const float*)d_in[3];
    bf16* ws   = (bf16*)d_ws;
    float* out = (float*)d_out;

    bf16* wq_bf = ws + 4 * QSZ;
    bf16* wo_bf = wq_bf + WQ_ELEMS;

    cvt_kernel <<<dim3(WQ_ELEMS / 256), 256, 0, stream>>>(w_qkv, w_out, wq_bf);
    qkv_kernel <<<dim3(144, Bn),   256, 0, stream>>>(x, wq_bf, ws);
    attn_kernel<<<dim3(1152),      256, 0, stream>>>(ws);
    out_kernel <<<dim3(36, Bn, 4), 256, 0, stream>>>(wo_bf, b_out, ws + 3 * QSZ, out);
}

// Round 10
// 139.951 us; speedup vs baseline: 1.4096x; 1.4096x over previous
//
#include <hip/hip_runtime.h>
#include <hip/hip_bf16.h>

typedef __bf16 bf16;
typedef bf16 bf16x8 __attribute__((ext_vector_type(8)));
typedef bf16 bf16x4 __attribute__((ext_vector_type(4)));
typedef float f32x4 __attribute__((ext_vector_type(4)));

#define Bn 8
#define Cdim 256
#define Nn 2304
#define NH 4
#define DH 32
#define HID 128
#define QSCALE (0.17677669529663687f * 1.4426950408889634f)
#define SMAX 14.0f
#define QSZ ((size_t)32 * Nn * DH)
#define WQ_ELEMS (3 * HID * Cdim)
#define WO_ELEMS (Cdim * HID)

// ---------------- Kernel 0: weight cvt + FRAG-MAJOR repack (gather) ----------
__global__ __launch_bounds__(256) void cvt_kernel(const float* __restrict__ wq,
                                                  const float* __restrict__ wo,
                                                  bf16* __restrict__ dst) {
    int d = blockIdx.x * 256 + threadIdx.x;
    {   // wq: 24 o-tiles, 8 kc
        int j = d & 7, lane = (d >> 3) & 63, kc = (d >> 9) & 7, ot = d >> 12;
        int o = ot * 16 + (lane & 15), c = kc * 32 + (lane >> 4) * 8 + j;
        dst[d] = (bf16)wq[o * Cdim + c];
    }
    if (d < WO_ELEMS) {   // wo: 16 o-tiles, 4 kc
        int j = d & 7, lane = (d >> 3) & 63, kc = (d >> 9) & 3, ot = d >> 11;
        int o = ot * 16 + (lane & 15), c = kc * 32 + (lane >> 4) * 8 + j;
        dst[WQ_ELEMS + d] = (bf16)wo[o * HID + c];
    }
}

// ---------------- Kernel 1: QKV projection (direct global gather, no LDS) ----
__global__ __launch_bounds__(256) void qkv_kernel(const float* __restrict__ x,
                                                  const bf16* __restrict__ w,
                                                  bf16* __restrict__ ws) {
    const int p0  = blockIdx.x * 16;
    const int b   = blockIdx.y;
    const int tid = threadIdx.x;
    const int lane = tid & 63, w4 = tid >> 6, l16 = lane & 15, quad = lane >> 4;
    const float* xb = x + (size_t)b * Cdim * Nn + p0 + l16;

    bf16x8 bx[8];
    #pragma unroll
    for (int kc = 0; kc < 8; ++kc)
        #pragma unroll
        for (int jj = 0; jj < 8; ++jj)
            bx[kc][jj] = (bf16)xb[(size_t)(kc * 32 + quad * 8 + jj) * Nn];

    const int p = p0 + l16;
    #pragma unroll 1
    for (int oi = 0; oi < 6; ++oi) {
        const int ot = w4 * 6 + oi;
        f32x4 acc0 = {0.f, 0.f, 0.f, 0.f};
        f32x4 acc1 = {0.f, 0.f, 0.f, 0.f};
        #pragma unroll
        for (int kc = 0; kc < 4; ++kc) {
            bf16x8 aw0 = *(const bf16x8*)&w[(((size_t)ot * 8 + kc) * 64 + lane) * 8];
            bf16x8 aw1 = *(const bf16x8*)&w[(((size_t)ot * 8 + kc + 4) * 64 + lane) * 8];
            acc0 = __builtin_amdgcn_mfma_f32_16x16x32_bf16(aw0, bx[kc],     acc0, 0, 0, 0);
            acc1 = __builtin_amdgcn_mfma_f32_16x16x32_bf16(aw1, bx[kc + 4], acc1, 0, 0, 0);
        }
        const int obase = ot * 16 + quad * 4;
        const int t     = obase >> 7;
        const int rem   = obase & 127;
        const int h     = rem >> 5;
        const int dbase = rem & 31;
        if (t == 2) {
            bf16* vt = ws + 2 * QSZ + (size_t)(b * NH + h) * DH * Nn;
            #pragma unroll
            for (int r = 0; r < 4; ++r)
                vt[(size_t)(dbase + r) * Nn + p] = (bf16)(acc0[r] + acc1[r]);
        } else if (t == 1) {
            bf16x4 v4;
            #pragma unroll
            for (int r = 0; r < 4; ++r) v4[r] = (bf16)(acc0[r] + acc1[r]);
            bf16* kf = ws + QSZ + (size_t)(b * NH + h) * Nn * DH;
            const int addr = ((p >> 4) * 64 + (dbase >> 3) * 16 + (p & 15)) * 8 + (dbase & 7);
            *(bf16x4*)&kf[addr] = v4;
        } else {
            bf16x4 v4;
            #pragma unroll
            for (int r = 0; r < 4; ++r) v4[r] = (bf16)((acc0[r] + acc1[r]) * QSCALE);
            size_t addr = ((size_t)(b * NH + h) * Nn + p) * DH + dbase;
            *(bf16x4*)&ws[addr] = v4;
        }
    }
}

// ---------------- Kernel 2: flash attention (64 rows/wave, no-spill) ---------
// Grid 1152, XCD-pinned. WG = 64 Q-rows; wave w owns j-quarter [w*576,+576),
// processes all 64 rows. Per-i-tile interleave (QK->exp2->LDS->PV per it)
// keeps live ranges short; launch_bounds(256,2) allows ~256 VGPR: no spill.
__global__ __launch_bounds__(256, 2) void attn_kernel(bf16* __restrict__ ws) {
    __shared__ alignas(16) char smem[34816];   // P: 4x2x2KB | combine ob+lb
    const int g   = blockIdx.x;
    const int grp = g >> 3;
    const int bh  = (g & 7) * 4 + grp / 36;
    const int i0  = (grp % 36) * 64;
    const int tid = threadIdx.x;
    const int lane = tid & 63, w4 = tid >> 6, l16 = lane & 15, quad = lane >> 4;
    const int jbase = w4 * 576;

    const bf16* Qb = ws + (size_t)bh * Nn * DH;
    const bf16* Kf = ws + QSZ + (size_t)bh * Nn * DH;       // frag-major
    const bf16* Vt = ws + 2 * QSZ + (size_t)bh * DH * Nn;   // [d][n]

    bf16x8 aq[4];
    #pragma unroll
    for (int it = 0; it < 4; ++it)
        aq[it] = *(const bf16x8*)&Qb[(size_t)(i0 + it * 16 + l16) * DH + quad * 8];

    f32x4 o[4][2];
    #pragma unroll
    for (int it = 0; it < 4; ++it) {
        o[it][0] = {0.f, 0.f, 0.f, 0.f};
        o[it][1] = {0.f, 0.f, 0.f, 0.f};
    }
    float lp[4] = {0.f, 0.f, 0.f, 0.f};
    const f32x4 negM = {-SMAX, -SMAX, -SMAX, -SMAX};

    const int swz = (l16 & 7) << 1;
    int wa[4];
    #pragma unroll
    for (int jt = 0; jt < 4; ++jt)
        wa[jt] = l16 * 64 + (((jt * 4) | quad) ^ swz) * 4;
    const int ra0 = l16 * 64 + ((quad * 2) ^ swz) * 4;
    const int ra1 = l16 * 64 + ((8 | (quad * 2)) ^ swz) * 4;
    bf16* pbuf = (bf16*)smem + w4 * 2048;      // two 1K-elem buffers per wave

    bf16x8 kf[4];
    {   const bf16* kp = &Kf[(size_t)(jbase >> 4) * 512 + lane * 8];
        #pragma unroll
        for (int jt = 0; jt < 4; ++jt) kf[jt] = *(const bf16x8*)&kp[jt * 512];
    }

    #pragma unroll 1
    for (int cc = 0; cc < 9; ++cc) {
        const int j0 = jbase + cc * 64;
        const bf16* vp = &Vt[j0];
        bf16x8 bv0 = *(const bf16x8*)&vp[(size_t)l16 * Nn + quad * 8];
        bf16x8 bv1 = *(const bf16x8*)&vp[(size_t)l16 * Nn + 32 + quad * 8];
        bf16x8 bv2 = *(const bf16x8*)&vp[(size_t)(l16 + 16) * Nn + quad * 8];
        bf16x8 bv3 = *(const bf16x8*)&vp[(size_t)(l16 + 16) * Nn + 32 + quad * 8];

        #pragma unroll
        for (int it = 0; it < 4; ++it) {
            bf16* pb = pbuf + (it & 1) * 1024;
            #pragma unroll
            for (int jt = 0; jt < 4; ++jt) {
                f32x4 st = __builtin_amdgcn_mfma_f32_16x16x32_bf16(kf[jt], aq[it], negM, 0, 0, 0);
                float e0 = __builtin_amdgcn_exp2f(st[0]);
                float e1 = __builtin_amdgcn_exp2f(st[1]);
                float e2 = __builtin_amdgcn_exp2f(st[2]);
                float e3 = __builtin_amdgcn_exp2f(st[3]);
                lp[it] += (e0 + e1) + (e2 + e3);
                bf16x4 pv4 = {(bf16)e0, (bf16)e1, (bf16)e2, (bf16)e3};
                *(bf16x4*)&pb[wa[jt]] = pv4;
            }
            const bf16x8 ap0 = *(const bf16x8*)&pb[ra0];
            const bf16x8 ap1 = *(const bf16x8*)&pb[ra1];
            o[it][0] = __builtin_amdgcn_mfma_f32_16x16x32_bf16(ap0, bv0, o[it][0], 0, 0, 0);
            o[it][0] = __builtin_amdgcn_mfma_f32_16x16x32_bf16(ap1, bv1, o[it][0], 0, 0, 0);
            o[it][1] = __builtin_amdgcn_mfma_f32_16x16x32_bf16(ap0, bv2, o[it][1], 0, 0, 0);
            o[it][1] = __builtin_amdgcn_mfma_f32_16x16x32_bf16(ap1, bv3, o[it][1], 0, 0, 0);
        }
        if (cc != 8) {   // prefetch next K after all QK uses of kf
            const bf16* kp = &Kf[(size_t)((j0 + 64) >> 4) * 512 + lane * 8];
            #pragma unroll
            for (int jt = 0; jt < 4; ++jt) kf[jt] = *(const bf16x8*)&kp[jt * 512];
        }
    }

    // l: finish sum over quads (j within wave)
    float lt[4];
    #pragma unroll
    for (int it = 0; it < 4; ++it) {
        float v = lp[it];
        v += __shfl_xor(v, 16);
        v += __shfl_xor(v, 32);
        lt[it] = v;
    }

    // ---- split-K combine across the 4 waves ----
    __syncthreads();
    float* ob = (float*)smem;            // [w][64 rows][33]
    float* lb = ob + 4 * 64 * 33;        // [w][64]
    #pragma unroll
    for (int it = 0; it < 4; ++it) {
        #pragma unroll
        for (int r = 0; r < 4; ++r) {
            ob[(w4 * 64 + it * 16 + quad * 4 + r) * 33 + l16]      = o[it][0][r];
            ob[(w4 * 64 + it * 16 + quad * 4 + r) * 33 + 16 + l16] = o[it][1][r];
        }
        if (quad == 0) lb[w4 * 64 + it * 16 + l16] = lt[it];
    }
    __syncthreads();

    bf16* Ab = ws + 3 * QSZ + (size_t)bh * Nn * DH;
    #pragma unroll
    for (int k = 0; k < 8; ++k) {
        const int idx = k * 256 + tid;
        const int row = idx >> 5, dd = idx & 31;
        float os = ob[row * 33 + dd] + ob[(64 + row) * 33 + dd]
                 + ob[(128 + row) * 33 + dd] + ob[(192 + row) * 33 + dd];
        float lsum = lb[row] + lb[64 + row] + lb[128 + row] + lb[192 + row];
        Ab[(size_t)(i0 + row) * DH + dd] = (bf16)(os / lsum);
    }
}

// ---------------- Kernel 3: output projection (z-split x4) -------------------
__global__ __launch_bounds__(256) void out_kernel(const bf16* __restrict__ wout,
                                                  const float* __restrict__ bout,
                                                  const bf16* __restrict__ Abuf,
                                                  float* __restrict__ out) {
    const int p0  = blockIdx.x * 64;
    const int b   = blockIdx.y;
    const int otb = blockIdx.z * 4;
    const int tid = threadIdx.x;
    const int lane = tid & 63, w4 = tid >> 6, l16 = lane & 15, quad = lane >> 4;
    const int p = p0 + w4 * 16 + l16;

    bf16x8 bfrag[4];
    #pragma unroll
    for (int h = 0; h < NH; ++h)
        bfrag[h] = *(const bf16x8*)&Abuf[((size_t)(b * NH + h) * Nn + p) * DH + quad * 8];

    #pragma unroll 1
    for (int oi = 0; oi < 4; ++oi) {
        const int ot = otb + oi;
        const int o0 = ot * 16;
        float4 b4 = *(const float4*)&bout[o0 + quad * 4];
        f32x4 acc0 = {b4.x, b4.y, b4.z, b4.w};
        f32x4 acc1 = {0.f, 0.f, 0.f, 0.f};
        #pragma unroll
        for (int kc = 0; kc < 2; ++kc) {
            bf16x8 aw0 = *(const bf16x8*)&wout[(((size_t)ot * 4 + kc) * 64 + lane) * 8];
            bf16x8 aw1 = *(const bf16x8*)&wout[(((size_t)ot * 4 + kc + 2) * 64 + lane) * 8];
            acc0 = __builtin_amdgcn_mfma_f32_16x16x32_bf16(aw0, bfrag[kc],     acc0, 0, 0, 0);
            acc1 = __builtin_amdgcn_mfma_f32_16x16x32_bf16(aw1, bfrag[kc + 2], acc1, 0, 0, 0);
        }
        #pragma unroll
        for (int r = 0; r < 4; ++r) {
            const int o = o0 + quad * 4 + r;
            out[((size_t)(b * Cdim + o)) * Nn + p] = acc0[r] + acc1[r];
        }
    }
}

extern "C" void kernel_launch(void* const* d_in, const int* in_sizes, int n_in,
                              void* d_out, int out_size, void* d_ws, size_t ws_size,
                              hipStream_t stream) {
    const float* x     = (const float*)d_in[0];
    const float* w_qkv = (const float*)d_in[1];
    const float* w_out = (const float*)d_in[2];
    const float* b_out = (const float*)d_in[3];
    bf16* ws   = (bf16*)d_ws;
    float* out = (float*)d_out;

    bf16* wq_bf = ws + 4 * QSZ;
    bf16* wo_bf = wq_bf + WQ_ELEMS;

    cvt_kernel <<<dim3(WQ_ELEMS / 256), 256, 0, stream>>>(w_qkv, w_out, wq_bf);
    qkv_kernel <<<dim3(144, Bn),   256, 0, stream>>>(x, wq_bf, ws);
    attn_kernel<<<dim3(1152),      256, 0, stream>>>(ws);
    out_kernel <<<dim3(36, Bn, 4), 256, 0, stream>>>(wo_bf, b_out, ws + 3 * QSZ, out);
}